// Round 15
// baseline (778.548 us; speedup 1.0000x reference)
//
#include <hip/hip_runtime.h>
#include <math.h>

#define BB 8
#define CIN 32
#define NN 10000
#define TTT 12
#define EE 160000
#define CSP 64
#define BT (BB*TTT)   // 96
#define NPAIR 48
#define EPSV 1e-5f

typedef __attribute__((ext_vector_type(8))) short bf16x8;
typedef __attribute__((ext_vector_type(4))) float f32x4;

static __device__ __forceinline__ float sigmoidf_(float v) {
    return __builtin_amdgcn_rcpf(1.f + __expf(-v));
}

static __device__ __forceinline__ short f2bf(float v) {
    unsigned u = __float_as_uint(v);
    u = (u + 0x7fffu + ((u >> 16) & 1u)) >> 16;
    return (short)u;
}
static __device__ __forceinline__ float lo16f(unsigned u) {
    return __uint_as_float(u << 16);
}
static __device__ __forceinline__ float hi16f(unsigned u) {
    return __uint_as_float(u & 0xffff0000u);
}
static __device__ __forceinline__ unsigned packbf(float a, float b) {
    return ((unsigned)(ushort)f2bf(a)) | (((unsigned)(ushort)f2bf(b)) << 16);
}

// ---------------- graph preprocessing ----------------
__global__ void k_deg(const int* __restrict__ ei, const float* __restrict__ ew,
                      float* __restrict__ deg) {
    int e = blockIdx.x * 256 + threadIdx.x;
    if (e < EE) atomicAdd(&deg[ei[e]], ew[e]);
}

__global__ void k_dinv(float* __restrict__ deg) {
    int n = blockIdx.x * 256 + threadIdx.x;
    if (n < NN) { float d = deg[n]; deg[n] = d > 0.f ? rsqrtf(d) : 0.f; }
}

__global__ void k_norm_cnt(const int* __restrict__ ei, const float* __restrict__ ew,
                           const float* __restrict__ dinv, float* __restrict__ nrm,
                           int* __restrict__ cnt) {
    int e = blockIdx.x * 256 + threadIdx.x;
    if (e < EE) {
        int r = ei[e], c = ei[EE + e];
        nrm[e] = -ew[e] * dinv[r] * dinv[c];
        atomicAdd(&cnt[c], 1);
    }
}

// ---- parallel scan: 40 blocks x 250 nodes ----
__global__ void k_scanA(const int* __restrict__ cnt, int* __restrict__ offs,
                        int* __restrict__ bsum) {
    __shared__ int sh[256];
    int b = blockIdx.x, t = threadIdx.x;
    int i = b * 250 + t;
    int v = (t < 250) ? cnt[i] : 0;
    sh[t] = v;
    __syncthreads();
    for (int off = 1; off < 256; off <<= 1) {
        int tv = (t >= off) ? sh[t - off] : 0;
        __syncthreads();
        sh[t] += tv;
        __syncthreads();
    }
    if (t < 250) offs[i] = sh[t] - v;    // local exclusive
    if (t == 255) bsum[b] = sh[255];
}

__global__ void k_scanB(const int* __restrict__ bsum, int* __restrict__ offs,
                        int* __restrict__ cursor) {
    int b = blockIdx.x, t = threadIdx.x;
    int base = 0;
    for (int j = 0; j < b; ++j) base += bsum[j];
    int i = b * 250 + t;
    if (t < 250) {
        int o = offs[i] + base;
        offs[i] = o;
        cursor[i] = o;
    }
    if (b == 39 && t == 0) offs[NN] = base + bsum[39];
}

// packed CSR: (w_bf16 << 16) | src
__global__ void k_fill(const int* __restrict__ ei, const float* __restrict__ nrm,
                       int* __restrict__ cursor, unsigned* __restrict__ csrp) {
    int e = blockIdx.x * 256 + threadIdx.x;
    if (e < EE) {
        int cdst = ei[EE + e];
        int p = atomicAdd(&cursor[cdst], 1);
        csrp[p] = (((unsigned)(ushort)f2bf(nrm[e])) << 16) | (unsigned)ei[e];
    }
}

// ---------------- weight conversion: per-tap transposed layouts ----------------
__global__ void k_cvt_w(const float* __restrict__ wg1, const float* __restrict__ wg2,
                        const float* __restrict__ wr, const float* __restrict__ cwf,
                        short* __restrict__ wtap1, short* __restrict__ wtap2,
                        short* __restrict__ o3, short* __restrict__ wt02,
                        short* __restrict__ wt1, short* __restrict__ wt2) {
    int i = blockIdx.x * 256 + threadIdx.x;
    if (i < 12288) {
        int kk = i / 4096, r = i % 4096, cc = r >> 5, ci = r & 31;
        wtap1[i] = f2bf(wg1[cc * 96 + ci * 3 + kk]);
    }
    if (i < 24576) {
        int kk = i / 8192, r = i % 8192, cc = r >> 6, c = r & 63;
        wtap2[i] = f2bf(wg2[cc * 192 + c * 3 + kk]);
    }
    if (i < 2048)  o3[i] = f2bf(wr[i]);
    if (i < 4096) {
        int cout = i >> 6, cin = i & 63;
        float w0 = cwf[cin * 64 + cout];
        float w1 = cwf[4096 + cin * 64 + cout];
        float w2 = cwf[8192 + cin * 64 + cout];
        wt02[i] = f2bf(w0 - w2);
        wt1[i]  = f2bf(w1);
        wt2[i]  = f2bf(w2);
    }
}

// ---------------- temporal block 1 (MFMA, shifted-tap) -> h1 bf16 pair layout ----------------
__global__ __launch_bounds__(256, 6) void k_tconv1_mfma(
    const float* __restrict__ x, const short* __restrict__ wtap,
    const float* __restrict__ bg, const float* __restrict__ gam,
    const float* __restrict__ bet, const float* __restrict__ mean,
    const float* __restrict__ var, ushort* __restrict__ h1)
{
    __shared__ short Hs[4][14][40];
    int bi = blockIdx.x;
    int b = bi / 2500;
    int n0 = (bi % 2500) * 4;
    int tid = threadIdx.x;

    if (tid < 128) {
        int n = tid >> 5, ci = tid & 31;
        const float* xp = x + ((size_t)(b * CIN + ci) * NN + n0 + n) * 12;
        float4 a0 = *(const float4*)(xp);
        float4 a1 = *(const float4*)(xp + 4);
        float4 a2 = *(const float4*)(xp + 8);
        short* d = &Hs[n][0][ci];
        d[0] = 0; d[13 * 40] = 0;
        d[1 * 40] = f2bf(a0.x); d[2 * 40] = f2bf(a0.y); d[3 * 40] = f2bf(a0.z);
        d[4 * 40] = f2bf(a0.w); d[5 * 40] = f2bf(a1.x); d[6 * 40] = f2bf(a1.y);
        d[7 * 40] = f2bf(a1.z); d[8 * 40] = f2bf(a1.w); d[9 * 40] = f2bf(a2.x);
        d[10 * 40] = f2bf(a2.y); d[11 * 40] = f2bf(a2.z); d[12 * 40] = f2bf(a2.w);
    }
    __syncthreads();

    int w = tid >> 6, l = tid & 63, lr = l & 15, lq = l >> 4;
    int nct[3], tct[3];
#pragma unroll
    for (int ct = 0; ct < 3; ++ct) {
        int col = ct * 16 + lr;
        nct[ct] = col / 12; tct[ct] = col % 12;
    }
    f32x4 aP[3], aQ[3];
#pragma unroll
    for (int m = 0; m < 3; ++m) { aP[m] = (f32x4){0,0,0,0}; aQ[m] = (f32x4){0,0,0,0}; }

#pragma unroll
    for (int kk = 0; kk < 3; ++kk) {
        bf16x8 wp = *(const bf16x8*)(wtap + ((kk * 128 + w * 16 + lr) * 32 + lq * 8));
        bf16x8 wq = *(const bf16x8*)(wtap + ((kk * 128 + 64 + w * 16 + lr) * 32 + lq * 8));
#pragma unroll
        for (int ct = 0; ct < 3; ++ct) {
            bf16x8 im = *(const bf16x8*)&Hs[nct[ct]][tct[ct] + kk][lq * 8];
            aP[ct] = __builtin_amdgcn_mfma_f32_16x16x32_bf16(im, wp, aP[ct], 0, 0, 0);
            aQ[ct] = __builtin_amdgcn_mfma_f32_16x16x32_bf16(im, wq, aQ[ct], 0, 0, 0);
        }
    }

    int c = w * 16 + lr;
    float bp = bg[c], bq = bg[64 + c];
    float sc = gam[c] * rsqrtf(var[c] + EPSV);
    float mn = mean[c], be = bet[c];
#pragma unroll
    for (int mt = 0; mt < 3; ++mt) {
#pragma unroll
        for (int j = 0; j < 4; ++j) {
            int row = mt * 16 + lq * 4 + j;
            int n = n0 + row / 12, t = row % 12;
            float h = (aP[mt][j] + bp) * sigmoidf_(aQ[mt][j] + bq);
            h1[((size_t)(b * 6 + (t >> 1)) * NN + n) * 128 + (t & 1) * 64 + c] =
                (ushort)f2bf((h - mn) * sc + be);
        }
    }
}

// ---------------- fused gather1 + Cheb einsum (MFMA), XCD-pinned ----------------
// grid = 15024 = 8 xcd * 6 pairs * 313 chunks of 32 nodes
// offs staged in LDS; self-row load stays in-loop (round-13 placement: small L2 footprint)
__global__ __launch_bounds__(256, 8) void k_spatial(
    const ushort* __restrict__ h1, const int* __restrict__ offs,
    const unsigned* __restrict__ csr,
    const short* __restrict__ wt02, const short* __restrict__ wt1,
    const short* __restrict__ wt2, const float* __restrict__ cb,
    ushort* __restrict__ O, ushort* __restrict__ U)
{
    __shared__ short Al[64][72];
    __shared__ short Gl[64][72];
    __shared__ int offsS[33];
    int tid = threadIdx.x;
    int bi = blockIdx.x;
    int xcd = bi & 7, r = bi >> 3;
    int jp = r / 313, ck = r - jp * 313;
    int pair = xcd * 6 + jp;
    int n0 = ck * 32;

    const char* hp = (const char*)h1 + (size_t)pair * NN * 256;
    int w = tid >> 6, l = tid & 63;
    int snap = l >> 5, cp = l & 31;
    unsigned loff = (unsigned)(snap * 128 + cp * 4);

    if (tid < 33) {
        int idx = n0 + tid;
        offsS[tid] = offs[idx > NN ? NN : idx];
    }
    __syncthreads();

#pragma unroll
    for (int p = 0; p < 8; ++p) {
        int nl = p * 4 + w;
        int n = n0 + nl;
        float a0 = 0.f, a1 = 0.f, b0 = 0.f, b1 = 0.f;
        unsigned sv = 0;
        if (n < NN) {
            sv = *(const unsigned*)(hp + (((unsigned)n) << 8) + loff);
            int i  = __builtin_amdgcn_readfirstlane(offsS[nl]);
            int o1 = __builtin_amdgcn_readfirstlane(offsS[nl + 1]);
            for (; i + 7 < o1; i += 8) {
                unsigned e0 = csr[i], e1 = csr[i+1], e2 = csr[i+2], e3 = csr[i+3];
                unsigned e4 = csr[i+4], e5 = csr[i+5], e6 = csr[i+6], e7 = csr[i+7];
                unsigned r0 = *(const unsigned*)(hp + ((e0 & 0xffffu) << 8) + loff);
                unsigned r1 = *(const unsigned*)(hp + ((e1 & 0xffffu) << 8) + loff);
                unsigned r2 = *(const unsigned*)(hp + ((e2 & 0xffffu) << 8) + loff);
                unsigned r3 = *(const unsigned*)(hp + ((e3 & 0xffffu) << 8) + loff);
                unsigned r4 = *(const unsigned*)(hp + ((e4 & 0xffffu) << 8) + loff);
                unsigned r5 = *(const unsigned*)(hp + ((e5 & 0xffffu) << 8) + loff);
                unsigned r6 = *(const unsigned*)(hp + ((e6 & 0xffffu) << 8) + loff);
                unsigned r7 = *(const unsigned*)(hp + ((e7 & 0xffffu) << 8) + loff);
                float w0 = hi16f(e0), w1 = hi16f(e1), w2 = hi16f(e2), w3 = hi16f(e3);
                float w4 = hi16f(e4), w5 = hi16f(e5), w6 = hi16f(e6), w7 = hi16f(e7);
                a0 = fmaf(w0, lo16f(r0), a0); a1 = fmaf(w0, hi16f(r0), a1);
                b0 = fmaf(w1, lo16f(r1), b0); b1 = fmaf(w1, hi16f(r1), b1);
                a0 = fmaf(w2, lo16f(r2), a0); a1 = fmaf(w2, hi16f(r2), a1);
                b0 = fmaf(w3, lo16f(r3), b0); b1 = fmaf(w3, hi16f(r3), b1);
                a0 = fmaf(w4, lo16f(r4), a0); a1 = fmaf(w4, hi16f(r4), a1);
                b0 = fmaf(w5, lo16f(r5), b0); b1 = fmaf(w5, hi16f(r5), b1);
                a0 = fmaf(w6, lo16f(r6), a0); a1 = fmaf(w6, hi16f(r6), a1);
                b0 = fmaf(w7, lo16f(r7), b0); b1 = fmaf(w7, hi16f(r7), b1);
            }
            for (; i + 3 < o1; i += 4) {
                unsigned e0 = csr[i], e1 = csr[i+1], e2 = csr[i+2], e3 = csr[i+3];
                unsigned r0 = *(const unsigned*)(hp + ((e0 & 0xffffu) << 8) + loff);
                unsigned r1 = *(const unsigned*)(hp + ((e1 & 0xffffu) << 8) + loff);
                unsigned r2 = *(const unsigned*)(hp + ((e2 & 0xffffu) << 8) + loff);
                unsigned r3 = *(const unsigned*)(hp + ((e3 & 0xffffu) << 8) + loff);
                float w0 = hi16f(e0), w1 = hi16f(e1), w2 = hi16f(e2), w3 = hi16f(e3);
                a0 = fmaf(w0, lo16f(r0), a0); a1 = fmaf(w0, hi16f(r0), a1);
                b0 = fmaf(w1, lo16f(r1), b0); b1 = fmaf(w1, hi16f(r1), b1);
                a0 = fmaf(w2, lo16f(r2), a0); a1 = fmaf(w2, hi16f(r2), a1);
                b0 = fmaf(w3, lo16f(r3), b0); b1 = fmaf(w3, hi16f(r3), b1);
            }
            for (; i < o1; ++i) {
                unsigned e = csr[i];
                unsigned rr = *(const unsigned*)(hp + ((e & 0xffffu) << 8) + loff);
                float ww = hi16f(e);
                a0 = fmaf(ww, lo16f(rr), a0); a1 = fmaf(ww, hi16f(rr), a1);
            }
        }
        int row = snap * 32 + nl;
        *(unsigned*)&Al[row][cp * 2] = sv;
        *(unsigned*)&Gl[row][cp * 2] = packbf(a0 + b0, a1 + b1);
    }
    __syncthreads();

    int lr = l & 15, lq = l >> 4;
    bf16x8 af[2], gf[2];
#pragma unroll
    for (int ks = 0; ks < 2; ++ks) {
        af[ks] = *(const bf16x8*)&Al[w * 16 + lr][ks * 32 + lq * 8];
        gf[ks] = *(const bf16x8*)&Gl[w * 16 + lr][ks * 32 + lq * 8];
    }
    f32x4 ao[4], au[4];
#pragma unroll
    for (int ct = 0; ct < 4; ++ct) { ao[ct] = (f32x4){0,0,0,0}; au[ct] = (f32x4){0,0,0,0}; }
#pragma unroll
    for (int ct = 0; ct < 4; ++ct) {
#pragma unroll
        for (int ks = 0; ks < 2; ++ks) {
            int woff = (ct * 16 + lr) * 64 + ks * 32 + lq * 8;
            bf16x8 b02 = *(const bf16x8*)(wt02 + woff);
            bf16x8 b1  = *(const bf16x8*)(wt1 + woff);
            bf16x8 b2  = *(const bf16x8*)(wt2 + woff);
            ao[ct] = __builtin_amdgcn_mfma_f32_16x16x32_bf16(af[ks], b02, ao[ct], 0, 0, 0);
            ao[ct] = __builtin_amdgcn_mfma_f32_16x16x32_bf16(gf[ks], b1,  ao[ct], 0, 0, 0);
            au[ct] = __builtin_amdgcn_mfma_f32_16x16x32_bf16(gf[ks], b2,  au[ct], 0, 0, 0);
        }
    }
    __syncthreads();

#pragma unroll
    for (int ct = 0; ct < 4; ++ct) {
        float bb = cb[ct * 16 + lr];
#pragma unroll
        for (int j2 = 0; j2 < 4; ++j2) {
            int rowo = w * 16 + lq * 4 + j2;
            Al[rowo][ct * 16 + lr] = f2bf(ao[ct][j2] + bb);
            Gl[rowo][ct * 16 + lr] = f2bf(au[ct][j2]);
        }
    }
    __syncthreads();

    size_t obase = (size_t)pair * NN * 128;
#pragma unroll
    for (int rr2 = 0; rr2 < 2; ++rr2) {
        int idx = tid + rr2 * 256;
        int node = idx >> 4, part = idx & 15;
        int sn = part >> 3, seg = part & 7;
        int n = n0 + node;
        if (n < NN) {
            size_t off = obase + (size_t)n * 128 + sn * 64 + seg * 8;
            __builtin_nontemporal_store(*(const bf16x8*)&Al[sn * 32 + node][seg * 8],
                                        (bf16x8*)(O + off));
            __builtin_nontemporal_store(*(const bf16x8*)&Gl[sn * 32 + node][seg * 8],
                                        (bf16x8*)(U + off));
        }
    }
}

// ---------------- gather 2 + LayerNorm + ReLU, XCD-pinned, one wave per node ----------------
__global__ __launch_bounds__(256, 8) void k_gather2_ln(
    const ushort* __restrict__ O, const ushort* __restrict__ U,
    const int* __restrict__ offs, const unsigned* __restrict__ csr,
    const float* __restrict__ lng, const float* __restrict__ lnb,
    ushort* __restrict__ hln)
{
    __shared__ int offsS[17];
    int bi = blockIdx.x;
    int xcd = bi & 7, r = bi >> 3;
    int jp = r / 625, ck = r - jp * 625;
    int pair = xcd * 6 + jp;
    int ng = ck * 16;
    int tid = threadIdx.x;
    int w = tid >> 6, l = tid & 63;
    int snap = l >> 5, cp = l & 31;
    unsigned loff = (unsigned)(snap * 128 + cp * 4);
    const char* up = (const char*)U + (size_t)pair * NN * 256;
    const char* op = (const char*)O + (size_t)pair * NN * 256;
    ushort* hlp = hln + (size_t)pair * NN * 128;

    float2 gv = ((const float2*)lng)[cp];
    float2 bv = ((const float2*)lnb)[cp];

    if (tid < 17) offsS[tid] = offs[ng + tid];
    // pre-issue the 4 O-row loads
    unsigned ovA[4];
#pragma unroll
    for (int p = 0; p < 4; ++p) {
        int n = ng + p * 4 + w;
        ovA[p] = *(const unsigned*)(op + (((unsigned)n) << 8) + loff);
    }
    __syncthreads();

#pragma unroll
    for (int p = 0; p < 4; ++p) {
        int nl = p * 4 + w;
        int n = ng + nl;
        float a0 = 0.f, a1 = 0.f, b0 = 0.f, b1 = 0.f;
        int i  = __builtin_amdgcn_readfirstlane(offsS[nl]);
        int o1 = __builtin_amdgcn_readfirstlane(offsS[nl + 1]);
        for (; i + 7 < o1; i += 8) {
            unsigned e0 = csr[i], e1 = csr[i+1], e2 = csr[i+2], e3 = csr[i+3];
            unsigned e4 = csr[i+4], e5 = csr[i+5], e6 = csr[i+6], e7 = csr[i+7];
            unsigned r0 = *(const unsigned*)(up + ((e0 & 0xffffu) << 8) + loff);
            unsigned r1 = *(const unsigned*)(up + ((e1 & 0xffffu) << 8) + loff);
            unsigned r2 = *(const unsigned*)(up + ((e2 & 0xffffu) << 8) + loff);
            unsigned r3 = *(const unsigned*)(up + ((e3 & 0xffffu) << 8) + loff);
            unsigned r4 = *(const unsigned*)(up + ((e4 & 0xffffu) << 8) + loff);
            unsigned r5 = *(const unsigned*)(up + ((e5 & 0xffffu) << 8) + loff);
            unsigned r6 = *(const unsigned*)(up + ((e6 & 0xffffu) << 8) + loff);
            unsigned r7 = *(const unsigned*)(up + ((e7 & 0xffffu) << 8) + loff);
            float w0 = hi16f(e0), w1 = hi16f(e1), w2 = hi16f(e2), w3 = hi16f(e3);
            float w4 = hi16f(e4), w5 = hi16f(e5), w6 = hi16f(e6), w7 = hi16f(e7);
            a0 = fmaf(w0, lo16f(r0), a0); a1 = fmaf(w0, hi16f(r0), a1);
            b0 = fmaf(w1, lo16f(r1), b0); b1 = fmaf(w1, hi16f(r1), b1);
            a0 = fmaf(w2, lo16f(r2), a0); a1 = fmaf(w2, hi16f(r2), a1);
            b0 = fmaf(w3, lo16f(r3), b0); b1 = fmaf(w3, hi16f(r3), b1);
            a0 = fmaf(w4, lo16f(r4), a0); a1 = fmaf(w4, hi16f(r4), a1);
            b0 = fmaf(w5, lo16f(r5), b0); b1 = fmaf(w5, hi16f(r5), b1);
            a0 = fmaf(w6, lo16f(r6), a0); a1 = fmaf(w6, hi16f(r6), a1);
            b0 = fmaf(w7, lo16f(r7), b0); b1 = fmaf(w7, hi16f(r7), b1);
        }
        for (; i + 3 < o1; i += 4) {
            unsigned e0 = csr[i], e1 = csr[i+1], e2 = csr[i+2], e3 = csr[i+3];
            unsigned r0 = *(const unsigned*)(up + ((e0 & 0xffffu) << 8) + loff);
            unsigned r1 = *(const unsigned*)(up + ((e1 & 0xffffu) << 8) + loff);
            unsigned r2 = *(const unsigned*)(up + ((e2 & 0xffffu) << 8) + loff);
            unsigned r3 = *(const unsigned*)(up + ((e3 & 0xffffu) << 8) + loff);
            float w0 = hi16f(e0), w1 = hi16f(e1), w2 = hi16f(e2), w3 = hi16f(e3);
            a0 = fmaf(w0, lo16f(r0), a0); a1 = fmaf(w0, hi16f(r0), a1);
            b0 = fmaf(w1, lo16f(r1), b0); b1 = fmaf(w1, hi16f(r1), b1);
            a0 = fmaf(w2, lo16f(r2), a0); a1 = fmaf(w2, hi16f(r2), a1);
            b0 = fmaf(w3, lo16f(r3), b0); b1 = fmaf(w3, hi16f(r3), b1);
        }
        for (; i < o1; ++i) {
            unsigned e = csr[i];
            unsigned rr = *(const unsigned*)(up + ((e & 0xffffu) << 8) + loff);
            float ww = hi16f(e);
            a0 = fmaf(ww, lo16f(rr), a0); a1 = fmaf(ww, hi16f(rr), a1);
        }
        unsigned ov = ovA[p];
        float acc0 = lo16f(ov) + 2.f * (a0 + b0);
        float acc1 = hi16f(ov) + 2.f * (a1 + b1);
        float s1 = acc0 + acc1;
        float s2 = acc0 * acc0 + acc1 * acc1;
#pragma unroll
        for (int m = 16; m >= 1; m >>= 1) {
            s1 += __shfl_xor(s1, m);
            s2 += __shfl_xor(s2, m);
        }
        float mu = s1 * (1.f / 64.f);
        float vr = s2 * (1.f / 64.f) - mu * mu;
        float rstd = rsqrtf(vr + EPSV);
        float y0 = fmaxf((acc0 - mu) * rstd * gv.x + bv.x, 0.f);
        float y1 = fmaxf((acc1 - mu) * rstd * gv.y + bv.y, 0.f);
        __builtin_nontemporal_store(packbf(y0, y1),
            (unsigned*)(hlp + (size_t)n * 128 + snap * 64 + cp * 2));
    }
}

// ---------------- temporal block 2 + residual (MFMA, shifted-tap) ----------------
__global__ __launch_bounds__(256, 5) void k_tconv2_mfma(
    const ushort* __restrict__ hln, const float* __restrict__ x,
    const short* __restrict__ wtap, const short* __restrict__ wrbf,
    const float* __restrict__ bg, const float* __restrict__ gam,
    const float* __restrict__ bet, const float* __restrict__ mean,
    const float* __restrict__ var, const float* __restrict__ bres,
    float* __restrict__ out)
{
    __shared__ short Hs[4][14][72];
    __shared__ short Bx[48 * 40];
    int bi = blockIdx.x;
    int b = bi / 2500;
    int n0 = (bi % 2500) * 4;
    int tid = threadIdx.x;

    for (int j = tid; j < 384; j += 256) {
        int n = j / 96, rem = j % 96;
        int p = rem >> 4, seg = rem & 15;
        bf16x8 v = *(const bf16x8*)(hln + ((size_t)(b * 6 + p) * NN + n0 + n) * 128 + seg * 8);
        *(bf16x8*)&Hs[n][1 + 2 * p + (seg >> 3)][(seg & 7) * 8] = v;
    }
    if (tid < 64) {
        int n = tid >> 4, pt = tid & 15;
        bf16x8 z = (bf16x8){0,0,0,0,0,0,0,0};
        *(bf16x8*)&Hs[n][(pt >> 3) * 13][(pt & 7) * 8] = z;
    }
    for (int j = tid; j < 384; j += 256) {
        int ci = j / 12, r = j - ci * 12;
        const float* xp = x + ((size_t)(b * CIN + ci) * NN + n0) * 12 + r * 4;
        float4 v = *(const float4*)xp;
        float vv[4] = {v.x, v.y, v.z, v.w};
#pragma unroll
        for (int e = 0; e < 4; ++e) {
            int col = r * 4 + e;
            Bx[col * 40 + ci] = f2bf(vv[e]);
        }
    }
    __syncthreads();

    int w = tid >> 6, l = tid & 63, lr = l & 15, lq = l >> 4;
    int nct[3], tct[3];
#pragma unroll
    for (int ct = 0; ct < 3; ++ct) {
        int col = ct * 16 + lr;
        nct[ct] = col / 12; tct[ct] = col % 12;
    }
    f32x4 accP[3], accQ[3], accR[3];
#pragma unroll
    for (int m = 0; m < 3; ++m) {
        accP[m] = (f32x4){0,0,0,0}; accQ[m] = (f32x4){0,0,0,0}; accR[m] = (f32x4){0,0,0,0};
    }

#pragma unroll
    for (int kk = 0; kk < 3; ++kk) {
#pragma unroll
        for (int ks = 0; ks < 2; ++ks) {
            bf16x8 aP = *(const bf16x8*)(wtap + ((kk * 128 + w * 16 + lr) * 64 + ks * 32 + lq * 8));
            bf16x8 aQ = *(const bf16x8*)(wtap + ((kk * 128 + 64 + w * 16 + lr) * 64 + ks * 32 + lq * 8));
#pragma unroll
            for (int ct = 0; ct < 3; ++ct) {
                bf16x8 bfr = *(const bf16x8*)&Hs[nct[ct]][tct[ct] + kk][ks * 32 + lq * 8];
                accP[ct] = __builtin_amdgcn_mfma_f32_16x16x32_bf16(aP, bfr, accP[ct], 0, 0, 0);
                accQ[ct] = __builtin_amdgcn_mfma_f32_16x16x32_bf16(aQ, bfr, accQ[ct], 0, 0, 0);
            }
        }
    }
    {
        bf16x8 aR = *(const bf16x8*)(wrbf + ((w * 16 + lr) * 32 + lq * 8));
#pragma unroll
        for (int ct = 0; ct < 3; ++ct) {
            bf16x8 bx = *(const bf16x8*)(&Bx[(ct * 16 + lr) * 40 + lq * 8]);
            accR[ct] = __builtin_amdgcn_mfma_f32_16x16x32_bf16(aR, bx, accR[ct], 0, 0, 0);
        }
    }

    float bpv[4], bqv[4], scv[4], mnv[4], bev[4], brv[4];
#pragma unroll
    for (int j = 0; j < 4; ++j) {
        int cj = w * 16 + lq * 4 + j;
        bpv[j] = bg[cj]; bqv[j] = bg[64 + cj];
        scv[j] = gam[cj] * rsqrtf(var[cj] + EPSV);
        mnv[j] = mean[cj]; bev[j] = bet[cj]; brv[j] = bres[cj];
    }
#pragma unroll
    for (int ct = 0; ct < 3; ++ct) {
        int col = ct * 16 + lr;
        int n = n0 + col / 12, t = col % 12;
#pragma unroll
        for (int j = 0; j < 4; ++j) {
            int cj = w * 16 + lq * 4 + j;
            float h = (accP[ct][j] + bpv[j]) * sigmoidf_(accQ[ct][j] + bqv[j]);
            float o = (h - mnv[j]) * scv[j] + bev[j] + accR[ct][j] + brv[j];
            __builtin_nontemporal_store(o, &out[((size_t)(b * 64 + cj) * NN + n) * 12 + t]);
        }
    }
}

extern "C" void kernel_launch(void* const* d_in, const int* in_sizes, int n_in,
                              void* d_out, int out_size, void* d_ws, size_t ws_size,
                              hipStream_t stream)
{
    const float* x   = (const float*)d_in[0];
    const int*   ei  = (const int*)d_in[1];
    const float* ew  = (const float*)d_in[2];
    const float* wg1 = (const float*)d_in[3];
    const float* bg1 = (const float*)d_in[4];
    const float* g1  = (const float*)d_in[5];
    const float* be1 = (const float*)d_in[6];
    const float* m1  = (const float*)d_in[7];
    const float* v1  = (const float*)d_in[8];
    const float* cw  = (const float*)d_in[9];
    const float* cb  = (const float*)d_in[10];
    const float* lng = (const float*)d_in[11];
    const float* lnb = (const float*)d_in[12];
    const float* wg2 = (const float*)d_in[13];
    const float* bg2 = (const float*)d_in[14];
    const float* g2  = (const float*)d_in[15];
    const float* be2 = (const float*)d_in[16];
    const float* m2  = (const float*)d_in[17];
    const float* v2  = (const float*)d_in[18];
    const float* wr  = (const float*)d_in[19];
    const float* br  = (const float*)d_in[20];

    char* w = (char*)d_ws;
    short* wtap1 = (short*)w;  w += 12288 * 2;
    short* wtap2 = (short*)w;  w += 24576 * 2;
    short* wrbf  = (short*)w;  w += 2048 * 2;
    short* wt02  = (short*)w;  w += 4096 * 2;
    short* wt1   = (short*)w;  w += 4096 * 2;
    short* wt2   = (short*)w;  w += 4096 * 2;
    ushort* h1   = (ushort*)w; w += (size_t)NPAIR * NN * 128 * 2;  // 122.88 MB (reused as hln)
    ushort* O    = (ushort*)w; w += (size_t)NPAIR * NN * 128 * 2;  // 122.88 MB
    float* deg   = (float*)w;  w += NN * 4;
    int*   cnt   = (int*)w;    w += NN * 4;
    int*   offs  = (int*)w;    w += (NN + 1) * 4;
    int*   cursor= (int*)w;    w += NN * 4;
    int*   bsum  = (int*)w;    w += 64 * 4;
    float* nrm   = (float*)w;  w += EE * 4;
    unsigned* csr = (unsigned*)w; w += EE * 4;
    ushort* U = (ushort*)d_out;   // reuse output buffer as U field (bf16)

    hipMemsetAsync(deg, 0, NN * 4 * 2, stream);   // deg + cnt

    k_deg<<<625, 256, 0, stream>>>(ei, ew, deg);
    k_dinv<<<40, 256, 0, stream>>>(deg);
    k_norm_cnt<<<625, 256, 0, stream>>>(ei, ew, deg, nrm, cnt);
    k_scanA<<<40, 256, 0, stream>>>(cnt, offs, bsum);
    k_scanB<<<40, 256, 0, stream>>>(bsum, offs, cursor);
    k_fill<<<625, 256, 0, stream>>>(ei, nrm, cursor, csr);
    k_cvt_w<<<96, 256, 0, stream>>>(wg1, wg2, wr, cw, wtap1, wtap2, wrbf, wt02, wt1, wt2);

    k_tconv1_mfma<<<BB * 2500, 256, 0, stream>>>(x, wtap1, bg1, g1, be1, m1, v1, h1);
    k_spatial<<<8 * 6 * 313, 256, 0, stream>>>(h1, offs, csr, wt02, wt1, wt2, cb, O, U);
    k_gather2_ln<<<8 * 6 * 625, 256, 0, stream>>>(O, U, offs, csr, lng, lnb, h1);
    k_tconv2_mfma<<<BB * 2500, 256, 0, stream>>>(h1, x, wtap2, wrbf, bg2, g2, be2, m2, v2, br,
                                                 (float*)d_out);
}

// Round 16
// 772.000 us; speedup vs baseline: 1.0085x; 1.0085x over previous
//
#include <hip/hip_runtime.h>
#include <math.h>

#define BB 8
#define CIN 32
#define NN 10000
#define TTT 12
#define EE 160000
#define CSP 64
#define BT (BB*TTT)   // 96
#define NPAIR 48
#define EPSV 1e-5f

typedef __attribute__((ext_vector_type(8))) short bf16x8;
typedef __attribute__((ext_vector_type(4))) float f32x4;

static __device__ __forceinline__ float sigmoidf_(float v) {
    return __builtin_amdgcn_rcpf(1.f + __expf(-v));
}

static __device__ __forceinline__ short f2bf(float v) {
    unsigned u = __float_as_uint(v);
    u = (u + 0x7fffu + ((u >> 16) & 1u)) >> 16;
    return (short)u;
}
static __device__ __forceinline__ float lo16f(unsigned u) {
    return __uint_as_float(u << 16);
}
static __device__ __forceinline__ float hi16f(unsigned u) {
    return __uint_as_float(u & 0xffff0000u);
}
static __device__ __forceinline__ unsigned packbf(float a, float b) {
    return ((unsigned)(ushort)f2bf(a)) | (((unsigned)(ushort)f2bf(b)) << 16);
}

// ---------------- graph preprocessing ----------------
__global__ void k_deg(const int* __restrict__ ei, const float* __restrict__ ew,
                      float* __restrict__ deg) {
    int e = blockIdx.x * 256 + threadIdx.x;
    if (e < EE) atomicAdd(&deg[ei[e]], ew[e]);
}

__global__ void k_dinv(float* __restrict__ deg) {
    int n = blockIdx.x * 256 + threadIdx.x;
    if (n < NN) { float d = deg[n]; deg[n] = d > 0.f ? rsqrtf(d) : 0.f; }
}

__global__ void k_norm_cnt(const int* __restrict__ ei, const float* __restrict__ ew,
                           const float* __restrict__ dinv, float* __restrict__ nrm,
                           int* __restrict__ cnt) {
    int e = blockIdx.x * 256 + threadIdx.x;
    if (e < EE) {
        int r = ei[e], c = ei[EE + e];
        nrm[e] = -ew[e] * dinv[r] * dinv[c];
        atomicAdd(&cnt[c], 1);
    }
}

// ---- parallel scan: 40 blocks x 250 nodes ----
__global__ void k_scanA(const int* __restrict__ cnt, int* __restrict__ offs,
                        int* __restrict__ bsum) {
    __shared__ int sh[256];
    int b = blockIdx.x, t = threadIdx.x;
    int i = b * 250 + t;
    int v = (t < 250) ? cnt[i] : 0;
    sh[t] = v;
    __syncthreads();
    for (int off = 1; off < 256; off <<= 1) {
        int tv = (t >= off) ? sh[t - off] : 0;
        __syncthreads();
        sh[t] += tv;
        __syncthreads();
    }
    if (t < 250) offs[i] = sh[t] - v;    // local exclusive
    if (t == 255) bsum[b] = sh[255];
}

__global__ void k_scanB(const int* __restrict__ bsum, int* __restrict__ offs,
                        int* __restrict__ cursor) {
    int b = blockIdx.x, t = threadIdx.x;
    int base = 0;
    for (int j = 0; j < b; ++j) base += bsum[j];
    int i = b * 250 + t;
    if (t < 250) {
        int o = offs[i] + base;
        offs[i] = o;
        cursor[i] = o;
    }
    if (b == 39 && t == 0) offs[NN] = base + bsum[39];
}

// packed CSR: (w_bf16 << 16) | src
__global__ void k_fill(const int* __restrict__ ei, const float* __restrict__ nrm,
                       int* __restrict__ cursor, unsigned* __restrict__ csrp) {
    int e = blockIdx.x * 256 + threadIdx.x;
    if (e < EE) {
        int cdst = ei[EE + e];
        int p = atomicAdd(&cursor[cdst], 1);
        csrp[p] = (((unsigned)(ushort)f2bf(nrm[e])) << 16) | (unsigned)ei[e];
    }
}

// ---------------- weight conversion: per-tap transposed layouts ----------------
__global__ void k_cvt_w(const float* __restrict__ wg1, const float* __restrict__ wg2,
                        const float* __restrict__ wr, const float* __restrict__ cwf,
                        short* __restrict__ wtap1, short* __restrict__ wtap2,
                        short* __restrict__ o3, short* __restrict__ wt02,
                        short* __restrict__ wt1, short* __restrict__ wt2) {
    int i = blockIdx.x * 256 + threadIdx.x;
    if (i < 12288) {
        int kk = i / 4096, r = i % 4096, cc = r >> 5, ci = r & 31;
        wtap1[i] = f2bf(wg1[cc * 96 + ci * 3 + kk]);
    }
    if (i < 24576) {
        int kk = i / 8192, r = i % 8192, cc = r >> 6, c = r & 63;
        wtap2[i] = f2bf(wg2[cc * 192 + c * 3 + kk]);
    }
    if (i < 2048)  o3[i] = f2bf(wr[i]);
    if (i < 4096) {
        int cout = i >> 6, cin = i & 63;
        float w0 = cwf[cin * 64 + cout];
        float w1 = cwf[4096 + cin * 64 + cout];
        float w2 = cwf[8192 + cin * 64 + cout];
        wt02[i] = f2bf(w0 - w2);
        wt1[i]  = f2bf(w1);
        wt2[i]  = f2bf(w2);
    }
}

// ---------------- temporal block 1 (MFMA, shifted-tap) -> h1 bf16 pair layout ----------------
__global__ __launch_bounds__(256, 6) void k_tconv1_mfma(
    const float* __restrict__ x, const short* __restrict__ wtap,
    const float* __restrict__ bg, const float* __restrict__ gam,
    const float* __restrict__ bet, const float* __restrict__ mean,
    const float* __restrict__ var, ushort* __restrict__ h1)
{
    __shared__ short Hs[4][14][40];
    int bi = blockIdx.x;
    int b = bi / 2500;
    int n0 = (bi % 2500) * 4;
    int tid = threadIdx.x;

    if (tid < 128) {
        int n = tid >> 5, ci = tid & 31;
        const float* xp = x + ((size_t)(b * CIN + ci) * NN + n0 + n) * 12;
        float4 a0 = *(const float4*)(xp);
        float4 a1 = *(const float4*)(xp + 4);
        float4 a2 = *(const float4*)(xp + 8);
        short* d = &Hs[n][0][ci];
        d[0] = 0; d[13 * 40] = 0;
        d[1 * 40] = f2bf(a0.x); d[2 * 40] = f2bf(a0.y); d[3 * 40] = f2bf(a0.z);
        d[4 * 40] = f2bf(a0.w); d[5 * 40] = f2bf(a1.x); d[6 * 40] = f2bf(a1.y);
        d[7 * 40] = f2bf(a1.z); d[8 * 40] = f2bf(a1.w); d[9 * 40] = f2bf(a2.x);
        d[10 * 40] = f2bf(a2.y); d[11 * 40] = f2bf(a2.z); d[12 * 40] = f2bf(a2.w);
    }
    __syncthreads();

    int w = tid >> 6, l = tid & 63, lr = l & 15, lq = l >> 4;
    int nct[3], tct[3];
#pragma unroll
    for (int ct = 0; ct < 3; ++ct) {
        int col = ct * 16 + lr;
        nct[ct] = col / 12; tct[ct] = col % 12;
    }
    f32x4 aP[3], aQ[3];
#pragma unroll
    for (int m = 0; m < 3; ++m) { aP[m] = (f32x4){0,0,0,0}; aQ[m] = (f32x4){0,0,0,0}; }

#pragma unroll
    for (int kk = 0; kk < 3; ++kk) {
        bf16x8 wp = *(const bf16x8*)(wtap + ((kk * 128 + w * 16 + lr) * 32 + lq * 8));
        bf16x8 wq = *(const bf16x8*)(wtap + ((kk * 128 + 64 + w * 16 + lr) * 32 + lq * 8));
#pragma unroll
        for (int ct = 0; ct < 3; ++ct) {
            bf16x8 im = *(const bf16x8*)&Hs[nct[ct]][tct[ct] + kk][lq * 8];
            aP[ct] = __builtin_amdgcn_mfma_f32_16x16x32_bf16(im, wp, aP[ct], 0, 0, 0);
            aQ[ct] = __builtin_amdgcn_mfma_f32_16x16x32_bf16(im, wq, aQ[ct], 0, 0, 0);
        }
    }

    int c = w * 16 + lr;
    float bp = bg[c], bq = bg[64 + c];
    float sc = gam[c] * rsqrtf(var[c] + EPSV);
    float mn = mean[c], be = bet[c];
#pragma unroll
    for (int mt = 0; mt < 3; ++mt) {
#pragma unroll
        for (int j = 0; j < 4; ++j) {
            int row = mt * 16 + lq * 4 + j;
            int n = n0 + row / 12, t = row % 12;
            float h = (aP[mt][j] + bp) * sigmoidf_(aQ[mt][j] + bq);
            h1[((size_t)(b * 6 + (t >> 1)) * NN + n) * 128 + (t & 1) * 64 + c] =
                (ushort)f2bf((h - mn) * sc + be);
        }
    }
}

// ---------------- fused gather1 + Cheb einsum (MFMA), XCD-pinned ----------------
// grid = 15024 = 8 xcd * 6 pairs * 313 chunks of 32 nodes  (round-13 body:
// direct scalar offs loads, self-row in-loop -> small L2 footprint)
__global__ __launch_bounds__(256, 8) void k_spatial(
    const ushort* __restrict__ h1, const int* __restrict__ offs,
    const unsigned* __restrict__ csr,
    const short* __restrict__ wt02, const short* __restrict__ wt1,
    const short* __restrict__ wt2, const float* __restrict__ cb,
    ushort* __restrict__ O, ushort* __restrict__ U)
{
    __shared__ short Al[64][72];
    __shared__ short Gl[64][72];
    int tid = threadIdx.x;
    int bi = blockIdx.x;
    int xcd = bi & 7, r = bi >> 3;
    int jp = r / 313, ck = r - jp * 313;
    int pair = xcd * 6 + jp;
    int n0 = ck * 32;

    const char* hp = (const char*)h1 + (size_t)pair * NN * 256;
    int w = tid >> 6, l = tid & 63;
    int snap = l >> 5, cp = l & 31;
    unsigned loff = (unsigned)(snap * 128 + cp * 4);

#pragma unroll
    for (int p = 0; p < 8; ++p) {
        int nl = p * 4 + w;
        int n = n0 + nl;
        float a0 = 0.f, a1 = 0.f, b0 = 0.f, b1 = 0.f;
        unsigned sv = 0;
        if (n < NN) {
            sv = *(const unsigned*)(hp + (((unsigned)n) << 8) + loff);
            int o0 = __builtin_amdgcn_readfirstlane(offs[n]);
            int o1 = __builtin_amdgcn_readfirstlane(offs[n + 1]);
            int i = o0;
            for (; i + 7 < o1; i += 8) {
                unsigned e0 = csr[i], e1 = csr[i+1], e2 = csr[i+2], e3 = csr[i+3];
                unsigned e4 = csr[i+4], e5 = csr[i+5], e6 = csr[i+6], e7 = csr[i+7];
                unsigned r0 = *(const unsigned*)(hp + ((e0 & 0xffffu) << 8) + loff);
                unsigned r1 = *(const unsigned*)(hp + ((e1 & 0xffffu) << 8) + loff);
                unsigned r2 = *(const unsigned*)(hp + ((e2 & 0xffffu) << 8) + loff);
                unsigned r3 = *(const unsigned*)(hp + ((e3 & 0xffffu) << 8) + loff);
                unsigned r4 = *(const unsigned*)(hp + ((e4 & 0xffffu) << 8) + loff);
                unsigned r5 = *(const unsigned*)(hp + ((e5 & 0xffffu) << 8) + loff);
                unsigned r6 = *(const unsigned*)(hp + ((e6 & 0xffffu) << 8) + loff);
                unsigned r7 = *(const unsigned*)(hp + ((e7 & 0xffffu) << 8) + loff);
                float w0 = hi16f(e0), w1 = hi16f(e1), w2 = hi16f(e2), w3 = hi16f(e3);
                float w4 = hi16f(e4), w5 = hi16f(e5), w6 = hi16f(e6), w7 = hi16f(e7);
                a0 = fmaf(w0, lo16f(r0), a0); a1 = fmaf(w0, hi16f(r0), a1);
                b0 = fmaf(w1, lo16f(r1), b0); b1 = fmaf(w1, hi16f(r1), b1);
                a0 = fmaf(w2, lo16f(r2), a0); a1 = fmaf(w2, hi16f(r2), a1);
                b0 = fmaf(w3, lo16f(r3), b0); b1 = fmaf(w3, hi16f(r3), b1);
                a0 = fmaf(w4, lo16f(r4), a0); a1 = fmaf(w4, hi16f(r4), a1);
                b0 = fmaf(w5, lo16f(r5), b0); b1 = fmaf(w5, hi16f(r5), b1);
                a0 = fmaf(w6, lo16f(r6), a0); a1 = fmaf(w6, hi16f(r6), a1);
                b0 = fmaf(w7, lo16f(r7), b0); b1 = fmaf(w7, hi16f(r7), b1);
            }
            for (; i + 3 < o1; i += 4) {
                unsigned e0 = csr[i], e1 = csr[i+1], e2 = csr[i+2], e3 = csr[i+3];
                unsigned r0 = *(const unsigned*)(hp + ((e0 & 0xffffu) << 8) + loff);
                unsigned r1 = *(const unsigned*)(hp + ((e1 & 0xffffu) << 8) + loff);
                unsigned r2 = *(const unsigned*)(hp + ((e2 & 0xffffu) << 8) + loff);
                unsigned r3 = *(const unsigned*)(hp + ((e3 & 0xffffu) << 8) + loff);
                float w0 = hi16f(e0), w1 = hi16f(e1), w2 = hi16f(e2), w3 = hi16f(e3);
                a0 = fmaf(w0, lo16f(r0), a0); a1 = fmaf(w0, hi16f(r0), a1);
                b0 = fmaf(w1, lo16f(r1), b0); b1 = fmaf(w1, hi16f(r1), b1);
                a0 = fmaf(w2, lo16f(r2), a0); a1 = fmaf(w2, hi16f(r2), a1);
                b0 = fmaf(w3, lo16f(r3), b0); b1 = fmaf(w3, hi16f(r3), b1);
            }
            for (; i < o1; ++i) {
                unsigned e = csr[i];
                unsigned rr = *(const unsigned*)(hp + ((e & 0xffffu) << 8) + loff);
                float ww = hi16f(e);
                a0 = fmaf(ww, lo16f(rr), a0); a1 = fmaf(ww, hi16f(rr), a1);
            }
        }
        int row = snap * 32 + nl;
        *(unsigned*)&Al[row][cp * 2] = sv;
        *(unsigned*)&Gl[row][cp * 2] = packbf(a0 + b0, a1 + b1);
    }
    __syncthreads();

    int lr = l & 15, lq = l >> 4;
    bf16x8 af[2], gf[2];
#pragma unroll
    for (int ks = 0; ks < 2; ++ks) {
        af[ks] = *(const bf16x8*)&Al[w * 16 + lr][ks * 32 + lq * 8];
        gf[ks] = *(const bf16x8*)&Gl[w * 16 + lr][ks * 32 + lq * 8];
    }
    f32x4 ao[4], au[4];
#pragma unroll
    for (int ct = 0; ct < 4; ++ct) { ao[ct] = (f32x4){0,0,0,0}; au[ct] = (f32x4){0,0,0,0}; }
#pragma unroll
    for (int ct = 0; ct < 4; ++ct) {
#pragma unroll
        for (int ks = 0; ks < 2; ++ks) {
            int woff = (ct * 16 + lr) * 64 + ks * 32 + lq * 8;
            bf16x8 b02 = *(const bf16x8*)(wt02 + woff);
            bf16x8 b1  = *(const bf16x8*)(wt1 + woff);
            bf16x8 b2  = *(const bf16x8*)(wt2 + woff);
            ao[ct] = __builtin_amdgcn_mfma_f32_16x16x32_bf16(af[ks], b02, ao[ct], 0, 0, 0);
            ao[ct] = __builtin_amdgcn_mfma_f32_16x16x32_bf16(gf[ks], b1,  ao[ct], 0, 0, 0);
            au[ct] = __builtin_amdgcn_mfma_f32_16x16x32_bf16(gf[ks], b2,  au[ct], 0, 0, 0);
        }
    }
    __syncthreads();

#pragma unroll
    for (int ct = 0; ct < 4; ++ct) {
        float bb = cb[ct * 16 + lr];
#pragma unroll
        for (int j2 = 0; j2 < 4; ++j2) {
            int rowo = w * 16 + lq * 4 + j2;
            Al[rowo][ct * 16 + lr] = f2bf(ao[ct][j2] + bb);
            Gl[rowo][ct * 16 + lr] = f2bf(au[ct][j2]);
        }
    }
    __syncthreads();

    size_t obase = (size_t)pair * NN * 128;
#pragma unroll
    for (int rr2 = 0; rr2 < 2; ++rr2) {
        int idx = tid + rr2 * 256;
        int node = idx >> 4, part = idx & 15;
        int sn = part >> 3, seg = part & 7;
        int n = n0 + node;
        if (n < NN) {
            size_t off = obase + (size_t)n * 128 + sn * 64 + seg * 8;
            __builtin_nontemporal_store(*(const bf16x8*)&Al[sn * 32 + node][seg * 8],
                                        (bf16x8*)(O + off));
            __builtin_nontemporal_store(*(const bf16x8*)&Gl[sn * 32 + node][seg * 8],
                                        (bf16x8*)(U + off));
        }
    }
}

// ---------------- gather 2 + LayerNorm + ReLU, XCD-pinned, one wave per node ----------------
__global__ __launch_bounds__(256, 8) void k_gather2_ln(
    const ushort* __restrict__ O, const ushort* __restrict__ U,
    const int* __restrict__ offs, const unsigned* __restrict__ csr,
    const float* __restrict__ lng, const float* __restrict__ lnb,
    ushort* __restrict__ hln)
{
    __shared__ int offsS[17];
    int bi = blockIdx.x;
    int xcd = bi & 7, r = bi >> 3;
    int jp = r / 625, ck = r - jp * 625;
    int pair = xcd * 6 + jp;
    int ng = ck * 16;
    int tid = threadIdx.x;
    int w = tid >> 6, l = tid & 63;
    int snap = l >> 5, cp = l & 31;
    unsigned loff = (unsigned)(snap * 128 + cp * 4);
    const char* up = (const char*)U + (size_t)pair * NN * 256;
    const char* op = (const char*)O + (size_t)pair * NN * 256;
    ushort* hlp = hln + (size_t)pair * NN * 128;

    float2 gv = ((const float2*)lng)[cp];
    float2 bv = ((const float2*)lnb)[cp];

    if (tid < 17) offsS[tid] = offs[ng + tid];
    // pre-issue the 4 O-row loads
    unsigned ovA[4];
#pragma unroll
    for (int p = 0; p < 4; ++p) {
        int n = ng + p * 4 + w;
        ovA[p] = *(const unsigned*)(op + (((unsigned)n) << 8) + loff);
    }
    __syncthreads();

#pragma unroll
    for (int p = 0; p < 4; ++p) {
        int nl = p * 4 + w;
        int n = ng + nl;
        float a0 = 0.f, a1 = 0.f, b0 = 0.f, b1 = 0.f;
        int i  = __builtin_amdgcn_readfirstlane(offsS[nl]);
        int o1 = __builtin_amdgcn_readfirstlane(offsS[nl + 1]);
        for (; i + 7 < o1; i += 8) {
            unsigned e0 = csr[i], e1 = csr[i+1], e2 = csr[i+2], e3 = csr[i+3];
            unsigned e4 = csr[i+4], e5 = csr[i+5], e6 = csr[i+6], e7 = csr[i+7];
            unsigned r0 = *(const unsigned*)(up + ((e0 & 0xffffu) << 8) + loff);
            unsigned r1 = *(const unsigned*)(up + ((e1 & 0xffffu) << 8) + loff);
            unsigned r2 = *(const unsigned*)(up + ((e2 & 0xffffu) << 8) + loff);
            unsigned r3 = *(const unsigned*)(up + ((e3 & 0xffffu) << 8) + loff);
            unsigned r4 = *(const unsigned*)(up + ((e4 & 0xffffu) << 8) + loff);
            unsigned r5 = *(const unsigned*)(up + ((e5 & 0xffffu) << 8) + loff);
            unsigned r6 = *(const unsigned*)(up + ((e6 & 0xffffu) << 8) + loff);
            unsigned r7 = *(const unsigned*)(up + ((e7 & 0xffffu) << 8) + loff);
            float w0 = hi16f(e0), w1 = hi16f(e1), w2 = hi16f(e2), w3 = hi16f(e3);
            float w4 = hi16f(e4), w5 = hi16f(e5), w6 = hi16f(e6), w7 = hi16f(e7);
            a0 = fmaf(w0, lo16f(r0), a0); a1 = fmaf(w0, hi16f(r0), a1);
            b0 = fmaf(w1, lo16f(r1), b0); b1 = fmaf(w1, hi16f(r1), b1);
            a0 = fmaf(w2, lo16f(r2), a0); a1 = fmaf(w2, hi16f(r2), a1);
            b0 = fmaf(w3, lo16f(r3), b0); b1 = fmaf(w3, hi16f(r3), b1);
            a0 = fmaf(w4, lo16f(r4), a0); a1 = fmaf(w4, hi16f(r4), a1);
            b0 = fmaf(w5, lo16f(r5), b0); b1 = fmaf(w5, hi16f(r5), b1);
            a0 = fmaf(w6, lo16f(r6), a0); a1 = fmaf(w6, hi16f(r6), a1);
            b0 = fmaf(w7, lo16f(r7), b0); b1 = fmaf(w7, hi16f(r7), b1);
        }
        for (; i + 3 < o1; i += 4) {
            unsigned e0 = csr[i], e1 = csr[i+1], e2 = csr[i+2], e3 = csr[i+3];
            unsigned r0 = *(const unsigned*)(up + ((e0 & 0xffffu) << 8) + loff);
            unsigned r1 = *(const unsigned*)(up + ((e1 & 0xffffu) << 8) + loff);
            unsigned r2 = *(const unsigned*)(up + ((e2 & 0xffffu) << 8) + loff);
            unsigned r3 = *(const unsigned*)(up + ((e3 & 0xffffu) << 8) + loff);
            float w0 = hi16f(e0), w1 = hi16f(e1), w2 = hi16f(e2), w3 = hi16f(e3);
            a0 = fmaf(w0, lo16f(r0), a0); a1 = fmaf(w0, hi16f(r0), a1);
            b0 = fmaf(w1, lo16f(r1), b0); b1 = fmaf(w1, hi16f(r1), b1);
            a0 = fmaf(w2, lo16f(r2), a0); a1 = fmaf(w2, hi16f(r2), a1);
            b0 = fmaf(w3, lo16f(r3), b0); b1 = fmaf(w3, hi16f(r3), b1);
        }
        for (; i < o1; ++i) {
            unsigned e = csr[i];
            unsigned rr = *(const unsigned*)(up + ((e & 0xffffu) << 8) + loff);
            float ww = hi16f(e);
            a0 = fmaf(ww, lo16f(rr), a0); a1 = fmaf(ww, hi16f(rr), a1);
        }
        unsigned ov = ovA[p];
        float acc0 = lo16f(ov) + 2.f * (a0 + b0);
        float acc1 = hi16f(ov) + 2.f * (a1 + b1);
        float s1 = acc0 + acc1;
        float s2 = acc0 * acc0 + acc1 * acc1;
#pragma unroll
        for (int m = 16; m >= 1; m >>= 1) {
            s1 += __shfl_xor(s1, m);
            s2 += __shfl_xor(s2, m);
        }
        float mu = s1 * (1.f / 64.f);
        float vr = s2 * (1.f / 64.f) - mu * mu;
        float rstd = rsqrtf(vr + EPSV);
        float y0 = fmaxf((acc0 - mu) * rstd * gv.x + bv.x, 0.f);
        float y1 = fmaxf((acc1 - mu) * rstd * gv.y + bv.y, 0.f);
        __builtin_nontemporal_store(packbf(y0, y1),
            (unsigned*)(hlp + (size_t)n * 128 + snap * 64 + cp * 2));
    }
}

// ---------------- temporal block 2 + residual (MFMA, shifted-tap) ----------------
__global__ __launch_bounds__(256, 5) void k_tconv2_mfma(
    const ushort* __restrict__ hln, const float* __restrict__ x,
    const short* __restrict__ wtap, const short* __restrict__ wrbf,
    const float* __restrict__ bg, const float* __restrict__ gam,
    const float* __restrict__ bet, const float* __restrict__ mean,
    const float* __restrict__ var, const float* __restrict__ bres,
    float* __restrict__ out)
{
    __shared__ short Hs[4][14][72];
    __shared__ short Bx[48 * 40];
    int bi = blockIdx.x;
    int b = bi / 2500;
    int n0 = (bi % 2500) * 4;
    int tid = threadIdx.x;

    for (int j = tid; j < 384; j += 256) {
        int n = j / 96, rem = j % 96;
        int p = rem >> 4, seg = rem & 15;
        bf16x8 v = *(const bf16x8*)(hln + ((size_t)(b * 6 + p) * NN + n0 + n) * 128 + seg * 8);
        *(bf16x8*)&Hs[n][1 + 2 * p + (seg >> 3)][(seg & 7) * 8] = v;
    }
    if (tid < 64) {
        int n = tid >> 4, pt = tid & 15;
        bf16x8 z = (bf16x8){0,0,0,0,0,0,0,0};
        *(bf16x8*)&Hs[n][(pt >> 3) * 13][(pt & 7) * 8] = z;
    }
    for (int j = tid; j < 384; j += 256) {
        int ci = j / 12, r = j - ci * 12;
        const float* xp = x + ((size_t)(b * CIN + ci) * NN + n0) * 12 + r * 4;
        float4 v = *(const float4*)xp;
        float vv[4] = {v.x, v.y, v.z, v.w};
#pragma unroll
        for (int e = 0; e < 4; ++e) {
            int col = r * 4 + e;
            Bx[col * 40 + ci] = f2bf(vv[e]);
        }
    }
    __syncthreads();

    int w = tid >> 6, l = tid & 63, lr = l & 15, lq = l >> 4;
    int nct[3], tct[3];
#pragma unroll
    for (int ct = 0; ct < 3; ++ct) {
        int col = ct * 16 + lr;
        nct[ct] = col / 12; tct[ct] = col % 12;
    }
    f32x4 accP[3], accQ[3], accR[3];
#pragma unroll
    for (int m = 0; m < 3; ++m) {
        accP[m] = (f32x4){0,0,0,0}; accQ[m] = (f32x4){0,0,0,0}; accR[m] = (f32x4){0,0,0,0};
    }

#pragma unroll
    for (int kk = 0; kk < 3; ++kk) {
#pragma unroll
        for (int ks = 0; ks < 2; ++ks) {
            bf16x8 aP = *(const bf16x8*)(wtap + ((kk * 128 + w * 16 + lr) * 64 + ks * 32 + lq * 8));
            bf16x8 aQ = *(const bf16x8*)(wtap + ((kk * 128 + 64 + w * 16 + lr) * 64 + ks * 32 + lq * 8));
#pragma unroll
            for (int ct = 0; ct < 3; ++ct) {
                bf16x8 bfr = *(const bf16x8*)&Hs[nct[ct]][tct[ct] + kk][ks * 32 + lq * 8];
                accP[ct] = __builtin_amdgcn_mfma_f32_16x16x32_bf16(aP, bfr, accP[ct], 0, 0, 0);
                accQ[ct] = __builtin_amdgcn_mfma_f32_16x16x32_bf16(aQ, bfr, accQ[ct], 0, 0, 0);
            }
        }
    }
    {
        bf16x8 aR = *(const bf16x8*)(wrbf + ((w * 16 + lr) * 32 + lq * 8));
#pragma unroll
        for (int ct = 0; ct < 3; ++ct) {
            bf16x8 bx = *(const bf16x8*)(&Bx[(ct * 16 + lr) * 40 + lq * 8]);
            accR[ct] = __builtin_amdgcn_mfma_f32_16x16x32_bf16(aR, bx, accR[ct], 0, 0, 0);
        }
    }

    float bpv[4], bqv[4], scv[4], mnv[4], bev[4], brv[4];
#pragma unroll
    for (int j = 0; j < 4; ++j) {
        int cj = w * 16 + lq * 4 + j;
        bpv[j] = bg[cj]; bqv[j] = bg[64 + cj];
        scv[j] = gam[cj] * rsqrtf(var[cj] + EPSV);
        mnv[j] = mean[cj]; bev[j] = bet[cj]; brv[j] = bres[cj];
    }
#pragma unroll
    for (int ct = 0; ct < 3; ++ct) {
        int col = ct * 16 + lr;
        int n = n0 + col / 12, t = col % 12;
#pragma unroll
        for (int j = 0; j < 4; ++j) {
            int cj = w * 16 + lq * 4 + j;
            float h = (accP[ct][j] + bpv[j]) * sigmoidf_(accQ[ct][j] + bqv[j]);
            float o = (h - mnv[j]) * scv[j] + bev[j] + accR[ct][j] + brv[j];
            __builtin_nontemporal_store(o, &out[((size_t)(b * 64 + cj) * NN + n) * 12 + t]);
        }
    }
}

extern "C" void kernel_launch(void* const* d_in, const int* in_sizes, int n_in,
                              void* d_out, int out_size, void* d_ws, size_t ws_size,
                              hipStream_t stream)
{
    const float* x   = (const float*)d_in[0];
    const int*   ei  = (const int*)d_in[1];
    const float* ew  = (const float*)d_in[2];
    const float* wg1 = (const float*)d_in[3];
    const float* bg1 = (const float*)d_in[4];
    const float* g1  = (const float*)d_in[5];
    const float* be1 = (const float*)d_in[6];
    const float* m1  = (const float*)d_in[7];
    const float* v1  = (const float*)d_in[8];
    const float* cw  = (const float*)d_in[9];
    const float* cb  = (const float*)d_in[10];
    const float* lng = (const float*)d_in[11];
    const float* lnb = (const float*)d_in[12];
    const float* wg2 = (const float*)d_in[13];
    const float* bg2 = (const float*)d_in[14];
    const float* g2  = (const float*)d_in[15];
    const float* be2 = (const float*)d_in[16];
    const float* m2  = (const float*)d_in[17];
    const float* v2  = (const float*)d_in[18];
    const float* wr  = (const float*)d_in[19];
    const float* br  = (const float*)d_in[20];

    char* w = (char*)d_ws;
    short* wtap1 = (short*)w;  w += 12288 * 2;
    short* wtap2 = (short*)w;  w += 24576 * 2;
    short* wrbf  = (short*)w;  w += 2048 * 2;
    short* wt02  = (short*)w;  w += 4096 * 2;
    short* wt1   = (short*)w;  w += 4096 * 2;
    short* wt2   = (short*)w;  w += 4096 * 2;
    ushort* h1   = (ushort*)w; w += (size_t)NPAIR * NN * 128 * 2;  // 122.88 MB (reused as hln)
    ushort* O    = (ushort*)w; w += (size_t)NPAIR * NN * 128 * 2;  // 122.88 MB
    float* deg   = (float*)w;  w += NN * 4;
    int*   cnt   = (int*)w;    w += NN * 4;
    int*   offs  = (int*)w;    w += (NN + 1) * 4;
    int*   cursor= (int*)w;    w += NN * 4;
    int*   bsum  = (int*)w;    w += 64 * 4;
    float* nrm   = (float*)w;  w += EE * 4;
    unsigned* csr = (unsigned*)w; w += EE * 4;
    ushort* U = (ushort*)d_out;   // reuse output buffer as U field (bf16)

    hipMemsetAsync(deg, 0, NN * 4 * 2, stream);   // deg + cnt

    k_deg<<<625, 256, 0, stream>>>(ei, ew, deg);
    k_dinv<<<40, 256, 0, stream>>>(deg);
    k_norm_cnt<<<625, 256, 0, stream>>>(ei, ew, deg, nrm, cnt);
    k_scanA<<<40, 256, 0, stream>>>(cnt, offs, bsum);
    k_scanB<<<40, 256, 0, stream>>>(bsum, offs, cursor);
    k_fill<<<625, 256, 0, stream>>>(ei, nrm, cursor, csr);
    k_cvt_w<<<96, 256, 0, stream>>>(wg1, wg2, wr, cw, wtap1, wtap2, wrbf, wt02, wt1, wt2);

    k_tconv1_mfma<<<BB * 2500, 256, 0, stream>>>(x, wtap1, bg1, g1, be1, m1, v1, h1);
    k_spatial<<<8 * 6 * 313, 256, 0, stream>>>(h1, offs, csr, wt02, wt1, wt2, cb, O, U);
    k_gather2_ln<<<8 * 6 * 625, 256, 0, stream>>>(O, U, offs, csr, lng, lnb, h1);
    k_tconv2_mfma<<<BB * 2500, 256, 0, stream>>>(h1, x, wtap2, wrbf, bg2, g2, be2, m2, v2, br,
                                                 (float*)d_out);
}